// Round 1
// baseline (565.623 us; speedup 1.0000x reference)
//
#include <hip/hip_runtime.h>

#define NJ 1024
#define NS 64
#define DETECT 0.5f

__global__ __launch_bounds__(256) void sold2_pairs_kernel(
    const float* __restrict__ junc,   // [N,2] (h,w)
    const float* __restrict__ heat,   // [H,W]
    float* __restrict__ line_out,     // [N,N] as float 0/1
    float* __restrict__ mean_out)     // [N,N]
{
    const int wave_in_block = threadIdx.x >> 6;
    const int lane = threadIdx.x & 63;
    const int p = (blockIdx.x << 2) + wave_in_block;   // pair id, 0..N*N-1
    const int i = p >> 10;                             // start junction
    const int j = p & 1023;                            // end junction

    const float2 ji = ((const float2*)junc)[i];
    const float2 jj = ((const float2*)junc)[j];

    // t = linspace(0,1,64); numpy endpoint: last element exactly 1.0
    const float step = 1.0f / 63.0f;
    const float t  = (lane == 63) ? 1.0f : (float)lane * step;
    const float om = 1.0f - t;

    float ch = ji.x * t + jj.x * om;
    float cw = ji.y * t + jj.y * om;
    ch = fminf(fmaxf(ch, 0.0f), 1023.0f);
    cw = fminf(fmaxf(cw, 0.0f), 1023.0f);

    const float hf = floorf(ch), hc = ceilf(ch);
    const float wf = floorf(cw), wc = ceilf(cw);
    const int hfi = (int)hf, hci = (int)hc;
    const int wfi = (int)wf, wci = (int)wc;

    const float* r0 = heat + (hfi << 10);
    const float* r1 = heat + (hci << 10);
    const float a00 = r0[wfi];
    const float a01 = r0[wci];
    const float a10 = r1[wfi];
    const float a11 = r1[wci];

    const float wh0 = hc - ch, wh1 = ch - hf;
    const float ww0 = wc - cw, ww1 = cw - wf;
    const float feat = a00 * wh0 * ww0 + a01 * wh0 * ww1
                     + a10 * wh1 * ww0 + a11 * wh1 * ww1;

    // inlier_ratio >= 0.99 over 64 samples  <=>  all 64 samples > 0.5
    const unsigned long long ball = __ballot(feat > DETECT);

    // wave sum for mean_feat
    float sum = feat;
    #pragma unroll
    for (int m = 1; m < 64; m <<= 1)
        sum += __shfl_xor(sum, m);
    const float mean = sum * (1.0f / 64.0f);

    if (lane == 0) {
        mean_out[p] = mean;
        const bool det = (mean > DETECT) && (ball == ~0ull) && (i != j);
        line_out[p] = det ? 1.0f : 0.0f;
    }
}

extern "C" void kernel_launch(void* const* d_in, const int* in_sizes, int n_in,
                              void* d_out, int out_size, void* d_ws, size_t ws_size,
                              hipStream_t stream) {
    const float* junc = (const float*)d_in[0];   // [1024,2] float32
    const float* heat = (const float*)d_in[1];   // [1024,1024] float32
    float* line_out = (float*)d_out;             // output 0: line_map as float
    float* mean_out = line_out + NJ * NJ;        // output 1: mean_feat

    const int num_pairs = NJ * NJ;               // 1M pairs, 1 wave each
    const int blocks = num_pairs / 4;            // 4 waves (256 threads) per block
    sold2_pairs_kernel<<<blocks, 256, 0, stream>>>(junc, heat, line_out, mean_out);
}

// Round 2
// 430.173 us; speedup vs baseline: 1.3149x; 1.3149x over previous
//
#include <hip/hip_runtime.h>

#define NJ 1024
#define DETECT 0.5f

typedef _Float16 half4v __attribute__((ext_vector_type(4)));

// Stage: packed[h][w] = 2x2 corner block (fp16): (h,w),(h,w+1),(h+1,w),(h+1,w+1)
__global__ __launch_bounds__(256) void pack_kernel(
    const float* __restrict__ heat, half4v* __restrict__ packed)
{
    const int idx = blockIdx.x * 256 + threadIdx.x;   // 0 .. 1M-1
    const int h = idx >> 10;
    const int w = idx & 1023;
    const int hn = (h < 1023) ? h + 1 : 1023;
    const int wn = (w < 1023) ? w + 1 : 1023;
    const float* r0 = heat + (h  << 10);
    const float* r1 = heat + (hn << 10);
    half4v c;
    c.x = (_Float16)r0[w];
    c.y = (_Float16)r0[wn];
    c.z = (_Float16)r1[w];
    c.w = (_Float16)r1[wn];
    packed[idx] = c;
}

__global__ __launch_bounds__(256) void sold2_pairs_kernel(
    const float* __restrict__ junc,     // [N,2] (h,w)
    const half4v* __restrict__ packed,  // [H,W] 2x2 fp16 corner blocks
    float* __restrict__ line_out,       // [N,N] as float 0/1
    float* __restrict__ mean_out)       // [N,N]
{
    const int wave_in_block = threadIdx.x >> 6;
    const int lane = threadIdx.x & 63;
    const int p = (blockIdx.x << 2) + wave_in_block;   // pair id
    const int i = p >> 10;
    const int j = p & 1023;

    const float2 ji = ((const float2*)junc)[i];
    const float2 jj = ((const float2*)junc)[j];

    // t = linspace(0,1,64); numpy endpoint semantics
    const float step = 1.0f / 63.0f;
    const float t  = (lane == 63) ? 1.0f : (float)lane * step;
    const float om = 1.0f - t;

    float ch = ji.x * t + jj.x * om;
    float cw = ji.y * t + jj.y * om;
    ch = fminf(fmaxf(ch, 0.0f), 1023.0f);
    cw = fminf(fmaxf(cw, 0.0f), 1023.0f);

    const float hf = floorf(ch), hc = ceilf(ch);
    const float wf = floorf(cw), wc = ceilf(cw);
    const int hfi = (int)hf;
    const int wfi = (int)wf;

    // One 8-byte gather replaces four 4-byte gathers.
    // If ceil!=floor, neighbor index is floor+1 == reference's ceil index.
    // If ceil==floor (integer coord), neighbor weight is exactly 0, value moot.
    const half4v c = packed[(hfi << 10) + wfi];
    const float a00 = (float)c.x;
    const float a01 = (float)c.y;
    const float a10 = (float)c.z;
    const float a11 = (float)c.w;

    const float wh0 = hc - ch, wh1 = ch - hf;
    const float ww0 = wc - cw, ww1 = cw - wf;
    const float feat = a00 * wh0 * ww0 + a01 * wh0 * ww1
                     + a10 * wh1 * ww0 + a11 * wh1 * ww1;

    // inlier_ratio >= 0.99 over 64 samples  <=>  all 64 samples > 0.5
    const unsigned long long ball = __ballot(feat > DETECT);

    float sum = feat;
    #pragma unroll
    for (int m = 1; m < 64; m <<= 1)
        sum += __shfl_xor(sum, m);
    const float mean = sum * (1.0f / 64.0f);

    if (lane == 0) {
        mean_out[p] = mean;
        const bool det = (mean > DETECT) && (ball == ~0ull) && (i != j);
        line_out[p] = det ? 1.0f : 0.0f;
    }
}

// Fallback (direct float gathers) in case ws_size < 8 MB.
__global__ __launch_bounds__(256) void sold2_pairs_direct_kernel(
    const float* __restrict__ junc,
    const float* __restrict__ heat,
    float* __restrict__ line_out,
    float* __restrict__ mean_out)
{
    const int wave_in_block = threadIdx.x >> 6;
    const int lane = threadIdx.x & 63;
    const int p = (blockIdx.x << 2) + wave_in_block;
    const int i = p >> 10;
    const int j = p & 1023;

    const float2 ji = ((const float2*)junc)[i];
    const float2 jj = ((const float2*)junc)[j];

    const float step = 1.0f / 63.0f;
    const float t  = (lane == 63) ? 1.0f : (float)lane * step;
    const float om = 1.0f - t;

    float ch = ji.x * t + jj.x * om;
    float cw = ji.y * t + jj.y * om;
    ch = fminf(fmaxf(ch, 0.0f), 1023.0f);
    cw = fminf(fmaxf(cw, 0.0f), 1023.0f);

    const float hf = floorf(ch), hc = ceilf(ch);
    const float wf = floorf(cw), wc = ceilf(cw);
    const int hfi = (int)hf, hci = (int)hc;
    const int wfi = (int)wf, wci = (int)wc;

    const float* r0 = heat + (hfi << 10);
    const float* r1 = heat + (hci << 10);
    const float a00 = r0[wfi];
    const float a01 = r0[wci];
    const float a10 = r1[wfi];
    const float a11 = r1[wci];

    const float wh0 = hc - ch, wh1 = ch - hf;
    const float ww0 = wc - cw, ww1 = cw - wf;
    const float feat = a00 * wh0 * ww0 + a01 * wh0 * ww1
                     + a10 * wh1 * ww0 + a11 * wh1 * ww1;

    const unsigned long long ball = __ballot(feat > DETECT);

    float sum = feat;
    #pragma unroll
    for (int m = 1; m < 64; m <<= 1)
        sum += __shfl_xor(sum, m);
    const float mean = sum * (1.0f / 64.0f);

    if (lane == 0) {
        mean_out[p] = mean;
        const bool det = (mean > DETECT) && (ball == ~0ull) && (i != j);
        line_out[p] = det ? 1.0f : 0.0f;
    }
}

extern "C" void kernel_launch(void* const* d_in, const int* in_sizes, int n_in,
                              void* d_out, int out_size, void* d_ws, size_t ws_size,
                              hipStream_t stream) {
    const float* junc = (const float*)d_in[0];   // [1024,2] float32
    const float* heat = (const float*)d_in[1];   // [1024,1024] float32
    float* line_out = (float*)d_out;
    float* mean_out = line_out + NJ * NJ;

    const int num_pairs = NJ * NJ;
    const int blocks = num_pairs / 4;            // 4 waves per block

    const size_t packed_bytes = (size_t)NJ * NJ * sizeof(half4v);  // 8 MB
    if (ws_size >= packed_bytes) {
        half4v* packed = (half4v*)d_ws;
        pack_kernel<<<NJ * NJ / 256, 256, 0, stream>>>(heat, packed);
        sold2_pairs_kernel<<<blocks, 256, 0, stream>>>(junc, packed, line_out, mean_out);
    } else {
        sold2_pairs_direct_kernel<<<blocks, 256, 0, stream>>>(junc, heat, line_out, mean_out);
    }
}

// Round 3
// 258.988 us; speedup vs baseline: 2.1840x; 1.6610x over previous
//
#include <hip/hip_runtime.h>

#define NJ 1024
#define DETECT 0.5f

typedef _Float16 half4v __attribute__((ext_vector_type(4)));

// Stage: packed[h][w] = 2x2 corner block (fp16): (h,w),(h,w+1),(h+1,w),(h+1,w+1)
__global__ __launch_bounds__(256) void pack_kernel(
    const float* __restrict__ heat, half4v* __restrict__ packed)
{
    const int idx = blockIdx.x * 256 + threadIdx.x;   // 0 .. 1M-1
    const int h = idx >> 10;
    const int w = idx & 1023;
    const int hn = (h < 1023) ? h + 1 : 1023;
    const int wn = (w < 1023) ? w + 1 : 1023;
    const float* r0 = heat + (h  << 10);
    const float* r1 = heat + (hn << 10);
    half4v c;
    c.x = (_Float16)r0[w];
    c.y = (_Float16)r0[wn];
    c.z = (_Float16)r1[w];
    c.w = (_Float16)r1[wn];
    packed[idx] = c;
}

// One THREAD per unordered pair; loop over the 64 samples.
// q = r*513 + c ; c==0 is the diagonal, c in [1,512] is circular offset.
// Each unordered pair with offset d in [1,511] appears exactly once;
// d==512 appears twice (idempotent double-write, harmless).
__global__ __launch_bounds__(256) void sold2_thread_kernel(
    const float* __restrict__ junc,     // [N,2] (h,w)
    const half4v* __restrict__ packed,  // [H,W] 2x2 fp16 corner blocks
    float* __restrict__ line_out,       // [N,N] float 0/1
    float* __restrict__ mean_out)       // [N,N]
{
    const int q = blockIdx.x * 256 + threadIdx.x;   // 0 .. 1024*513-1
    const int r = q / 513;                          // start junction i
    const int c = q - r * 513;                      // circular offset 0..512
    const int j = (r + c) & 1023;                   // end junction j

    const float2 jr = ((const float2*)junc)[r];
    const float2 jjc = ((const float2*)junc)[j];

    // ch(t) = jj + (ji - jj) * t   (i gets weight t per reference)
    const float dh = jr.x - jjc.x;
    const float dw = jr.y - jjc.y;
    const float step = 1.0f / 63.0f;

    float acc = 0.0f;
    float mn  = __builtin_inff();

    #pragma unroll
    for (int s0 = 0; s0 < 64; s0 += 8) {
        float chv[8], cwv[8];
        half4v cv[8];
        #pragma unroll
        for (int u = 0; u < 8; ++u) {
            const int s = s0 + u;
            const float t = (s == 63) ? 1.0f : (float)s * step;
            float ch = fmaf(dh, t, jjc.x);
            float cw = fmaf(dw, t, jjc.y);
            ch = fminf(fmaxf(ch, 0.0f), 1023.0f);
            cw = fminf(fmaxf(cw, 0.0f), 1023.0f);
            chv[u] = ch;
            cwv[u] = cw;
            const int hfi = (int)floorf(ch);
            const int wfi = (int)floorf(cw);
            cv[u] = packed[(hfi << 10) + wfi];
        }
        #pragma unroll
        for (int u = 0; u < 8; ++u) {
            const float ch = chv[u], cw = cwv[u];
            const float hf = floorf(ch), hc = ceilf(ch);
            const float wf = floorf(cw), wc = ceilf(cw);
            const half4v cc = cv[u];
            const float wh0 = hc - ch, wh1 = ch - hf;
            const float ww0 = wc - cw, ww1 = cw - wf;
            const float feat = (float)cc.x * (wh0 * ww0) + (float)cc.y * (wh0 * ww1)
                             + (float)cc.z * (wh1 * ww0) + (float)cc.w * (wh1 * ww1);
            acc += feat;
            mn = fminf(mn, feat);
        }
    }

    const float mean = acc * (1.0f / 64.0f);
    // inlier_ratio >= 0.99 over 64 samples <=> all 64 > 0.5 <=> min > 0.5
    const bool det = (mean > DETECT) && (mn > DETECT) && (c != 0);
    const float lv = det ? 1.0f : 0.0f;

    const int p1 = (r << 10) + j;
    const int p2 = (j << 10) + r;
    mean_out[p1] = mean;
    mean_out[p2] = mean;   // symmetric: identical sample set in reverse order
    line_out[p1] = lv;
    line_out[p2] = lv;
}

extern "C" void kernel_launch(void* const* d_in, const int* in_sizes, int n_in,
                              void* d_out, int out_size, void* d_ws, size_t ws_size,
                              hipStream_t stream) {
    const float* junc = (const float*)d_in[0];   // [1024,2] float32
    const float* heat = (const float*)d_in[1];   // [1024,1024] float32
    float* line_out = (float*)d_out;
    float* mean_out = line_out + NJ * NJ;

    half4v* packed = (half4v*)d_ws;              // 8 MB scratch
    pack_kernel<<<NJ * NJ / 256, 256, 0, stream>>>(heat, packed);

    const int total = NJ * 513;                  // 525,312 threads
    sold2_thread_kernel<<<total / 256, 256, 0, stream>>>(junc, packed, line_out, mean_out);
}

// Round 5
// 191.569 us; speedup vs baseline: 2.9526x; 1.3519x over previous
//
#include <hip/hip_runtime.h>

#define NJ 1024
#define DETECT 0.5f
#define RESCUE 0.4975f   // 0.5 minus u8 error bound (0.00196), with margin

// Stage: packed[h][w] = 2x2 corner block as 4x u8 fixed-point in one dword:
// byte0=(h,w) byte1=(h,w+1) byte2=(h+1,w) byte3=(h+1,w+1). 4 MB -> L2-resident.
__global__ __launch_bounds__(256) void pack_kernel(
    const float* __restrict__ heat, unsigned int* __restrict__ packed)
{
    const int idx = blockIdx.x * 256 + threadIdx.x;   // 0 .. 1M-1
    const int h = idx >> 10;
    const int w = idx & 1023;
    const int hn = (h < 1023) ? h + 1 : 1023;
    const int wn = (w < 1023) ? w + 1 : 1023;
    const float* r0 = heat + (h  << 10);
    const float* r1 = heat + (hn << 10);
    const unsigned int b0 = (unsigned int)__float2int_rn(r0[w]  * 255.0f);
    const unsigned int b1 = (unsigned int)__float2int_rn(r0[wn] * 255.0f);
    const unsigned int b2 = (unsigned int)__float2int_rn(r1[w]  * 255.0f);
    const unsigned int b3 = (unsigned int)__float2int_rn(r1[wn] * 255.0f);
    packed[idx] = b0 | (b1 << 8) | (b2 << 16) | (b3 << 24);
}

__device__ __forceinline__ float sample_t(int s) {
    // jnp.linspace(0,1,64) fp32 semantics (endpoint exactly 1.0)
    return (s == 63) ? 1.0f : (float)s * (1.0f / 63.0f);
}

// One thread per unordered pair (circular-offset enumeration), 64 samples each.
// q = r*513 + c ; c==0 diagonal, c in [1,512] circular offset; d==512 done
// twice (idempotent double-write).
__global__ __launch_bounds__(256) void sold2_thread_kernel(
    const float* __restrict__ junc,          // [N,2] (h,w)
    const float* __restrict__ heat,          // [H,W] fp32 (exact rescue path)
    const unsigned int* __restrict__ packed, // [H,W] u8x4 corner blocks
    float* __restrict__ line_out,            // [N,N] float 0/1
    float* __restrict__ mean_out)            // [N,N]
{
    const int q = blockIdx.x * 256 + threadIdx.x;   // 0 .. 1024*513-1
    const int r = q / 513;
    const int c = q - r * 513;
    const int j = (r + c) & 1023;

    const float2 jr  = ((const float2*)junc)[r];
    const float2 jjc = ((const float2*)junc)[j];

    float acc = 0.0f;           // in u8 counts (x255)
    float mn  = __builtin_inff();

    #pragma unroll
    for (int s0 = 0; s0 < 64; s0 += 16) {
        float chv[16], cwv[16];
        unsigned int cv[16];
        #pragma unroll
        for (int u = 0; u < 16; ++u) {
            const int s = s0 + u;
            const float t  = sample_t(s);
            const float om = 1.0f - t;
            // Reference op order: ji*t + jj*(1-t), contraction-proof.
            float ch = __fadd_rn(__fmul_rn(jr.x, t), __fmul_rn(jjc.x, om));
            float cw = __fadd_rn(__fmul_rn(jr.y, t), __fmul_rn(jjc.y, om));
            ch = fminf(fmaxf(ch, 0.0f), 1023.0f);
            cw = fminf(fmaxf(cw, 0.0f), 1023.0f);
            chv[u] = ch;
            cwv[u] = cw;
            const int hfi = (int)ch;   // trunc == floor for non-negative
            const int wfi = (int)cw;
            cv[u] = packed[(hfi << 10) + wfi];
        }
        #pragma unroll
        for (int u = 0; u < 16; ++u) {
            const float ch = chv[u], cw = cwv[u];
            const float hf = floorf(ch), hc = ceilf(ch);
            const float wf = floorf(cw), wc = ceilf(cw);
            const float wh0 = hc - ch, wh1 = ch - hf;
            const float ww0 = wc - cw, ww1 = cw - wf;
            const unsigned int cc = cv[u];
            const float a00 = (float)(cc & 0xffu);
            const float a01 = (float)((cc >> 8) & 0xffu);
            const float a10 = (float)((cc >> 16) & 0xffu);
            const float a11 = (float)(cc >> 24);
            const float feat = a00 * (wh0 * ww0) + a01 * (wh0 * ww1)
                             + a10 * (wh1 * ww0) + a11 * (wh1 * ww1);
            acc += feat;
            mn = fminf(mn, feat);
        }
    }

    float mean = acc * (1.0f / (255.0f * 64.0f));
    const float mns = mn * (1.0f / 255.0f);

    // Conservative candidate test: exact detection implies u8 min/mean > RESCUE.
    bool det = false;
    if ((mns > RESCUE) && (mean > RESCUE) && (c != 0)) {
        // Exact recompute from fp32 heatmap, reference op order.
        float acc2 = 0.0f;
        float mn2  = __builtin_inff();
        for (int s = 0; s < 64; ++s) {
            const float t  = sample_t(s);
            const float om = 1.0f - t;
            float ch = __fadd_rn(__fmul_rn(jr.x, t), __fmul_rn(jjc.x, om));
            float cw = __fadd_rn(__fmul_rn(jr.y, t), __fmul_rn(jjc.y, om));
            ch = fminf(fmaxf(ch, 0.0f), 1023.0f);
            cw = fminf(fmaxf(cw, 0.0f), 1023.0f);
            const float hf = floorf(ch), hc = ceilf(ch);
            const float wf = floorf(cw), wc = ceilf(cw);
            const int hfi = (int)hf, hci = (int)hc;
            const int wfi = (int)wf, wci = (int)wc;
            const float a00 = heat[(hfi << 10) + wfi];
            const float a01 = heat[(hfi << 10) + wci];
            const float a10 = heat[(hci << 10) + wfi];
            const float a11 = heat[(hci << 10) + wci];
            const float t1 = __fmul_rn(__fmul_rn(a00, __fsub_rn(hc, ch)), __fsub_rn(wc, cw));
            const float t2 = __fmul_rn(__fmul_rn(a01, __fsub_rn(hc, ch)), __fsub_rn(cw, wf));
            const float t3 = __fmul_rn(__fmul_rn(a10, __fsub_rn(ch, hf)), __fsub_rn(wc, cw));
            const float t4 = __fmul_rn(__fmul_rn(a11, __fsub_rn(ch, hf)), __fsub_rn(cw, wf));
            const float feat = __fadd_rn(__fadd_rn(__fadd_rn(t1, t2), t3), t4);
            acc2 += feat;
            mn2 = fminf(mn2, feat);
        }
        mean = acc2 * (1.0f / 64.0f);
        det = (mean > DETECT) && (mn2 > DETECT);
    }

    const float lv = det ? 1.0f : 0.0f;
    const int p1 = (r << 10) + j;
    const int p2 = (j << 10) + r;
    mean_out[p1] = mean;
    mean_out[p2] = mean;   // symmetric sample set (reverse order)
    line_out[p1] = lv;
    line_out[p2] = lv;
}

extern "C" void kernel_launch(void* const* d_in, const int* in_sizes, int n_in,
                              void* d_out, int out_size, void* d_ws, size_t ws_size,
                              hipStream_t stream) {
    const float* junc = (const float*)d_in[0];   // [1024,2] float32
    const float* heat = (const float*)d_in[1];   // [1024,1024] float32
    float* line_out = (float*)d_out;
    float* mean_out = line_out + NJ * NJ;

    unsigned int* packed = (unsigned int*)d_ws;  // 4 MB scratch
    pack_kernel<<<NJ * NJ / 256, 256, 0, stream>>>(heat, packed);

    const int total = NJ * 513;                  // 525,312 threads
    sold2_thread_kernel<<<total / 256, 256, 0, stream>>>(junc, heat, packed,
                                                         line_out, mean_out);
}

// Round 6
// 188.200 us; speedup vs baseline: 3.0054x; 1.0179x over previous
//
#include <hip/hip_runtime.h>

#define NJ 1024
#define DETECT 0.5f
#define RESCUE 0.4975f   // 0.5 minus u8 error bound (0.00196), with margin

// Stage: packed[h][w] = 2x2 corner block as 4x u8 fixed-point in one dword:
// byte0=(h,w) byte1=(h,w+1) byte2=(h+1,w) byte3=(h+1,w+1). 4 MB -> L2-resident.
// Vectorized: each thread packs 4 consecutive cells.
__global__ __launch_bounds__(256) void pack_kernel(
    const float* __restrict__ heat, uint4* __restrict__ packed4)
{
    const int idx = blockIdx.x * 256 + threadIdx.x;   // 0 .. 256K-1
    const int h = idx >> 8;                           // row
    const int w4 = (idx & 255) << 2;                  // first of 4 cells
    const int hn = (h < 1023) ? h + 1 : 1023;
    const float* r0 = heat + (h  << 10);
    const float* r1 = heat + (hn << 10);
    const float4 a = *(const float4*)(r0 + w4);
    const float4 b = *(const float4*)(r1 + w4);
    const int wnext = (w4 + 4 <= 1023) ? w4 + 4 : 1023;
    const float a4 = r0[wnext];
    const float b4 = r1[wnext];

    const float av[5] = {a.x, a.y, a.z, a.w, a4};
    const float bv[5] = {b.x, b.y, b.z, b.w, b4};
    unsigned int out[4];
    #pragma unroll
    for (int u = 0; u < 4; ++u) {
        const unsigned int c0 = (unsigned int)__float2int_rn(av[u]     * 255.0f);
        const unsigned int c1 = (unsigned int)__float2int_rn(av[u + 1] * 255.0f);
        const unsigned int c2 = (unsigned int)__float2int_rn(bv[u]     * 255.0f);
        const unsigned int c3 = (unsigned int)__float2int_rn(bv[u + 1] * 255.0f);
        out[u] = c0 | (c1 << 8) | (c2 << 16) | (c3 << 24);
    }
    packed4[idx] = make_uint4(out[0], out[1], out[2], out[3]);
}

__device__ __forceinline__ float sample_t(int s) {
    // jnp.linspace(0,1,64) fp32 semantics (endpoint exactly 1.0)
    return (s == 63) ? 1.0f : (float)s * (1.0f / 63.0f);
}

// One thread per pair-orientation in the band c in [0,512];
// q = r*513 + c ; j = (r+c) mod 1024. Writes ONLY its own cell (coalesced).
// The complement band (c in [513,1023]) is filled by mirror_kernel.
__global__ __launch_bounds__(256) void sold2_thread_kernel(
    const float* __restrict__ junc,          // [N,2] (h,w)
    const float* __restrict__ heat,          // [H,W] fp32 (exact rescue path)
    const unsigned int* __restrict__ packed, // [H,W] u8x4 corner blocks
    float* __restrict__ line_out,            // [N,N] float 0/1
    float* __restrict__ mean_out)            // [N,N]
{
    const int q = blockIdx.x * 256 + threadIdx.x;   // 0 .. 1024*513-1
    const int r = q / 513;
    const int c = q - r * 513;
    const int j = (r + c) & 1023;

    const float2 jr  = ((const float2*)junc)[r];
    const float2 jjc = ((const float2*)junc)[j];

    float acc = 0.0f;           // in u8 counts (x255)
    float mn  = __builtin_inff();

    #pragma unroll
    for (int s0 = 0; s0 < 64; s0 += 16) {
        float chv[16], cwv[16];
        unsigned int cv[16];
        #pragma unroll
        for (int u = 0; u < 16; ++u) {
            const int s = s0 + u;
            const float t  = sample_t(s);
            const float om = 1.0f - t;
            // Reference op order: ji*t + jj*(1-t), contraction-proof.
            float ch = __fadd_rn(__fmul_rn(jr.x, t), __fmul_rn(jjc.x, om));
            float cw = __fadd_rn(__fmul_rn(jr.y, t), __fmul_rn(jjc.y, om));
            ch = fminf(fmaxf(ch, 0.0f), 1023.0f);
            cw = fminf(fmaxf(cw, 0.0f), 1023.0f);
            chv[u] = ch;
            cwv[u] = cw;
            const int hfi = (int)ch;   // trunc == floor for non-negative
            const int wfi = (int)cw;
            cv[u] = packed[(hfi << 10) + wfi];
        }
        #pragma unroll
        for (int u = 0; u < 16; ++u) {
            const float ch = chv[u], cw = cwv[u];
            const float hf = floorf(ch), hc = ceilf(ch);
            const float wf = floorf(cw), wc = ceilf(cw);
            const float wh0 = hc - ch, wh1 = ch - hf;
            const float ww0 = wc - cw, ww1 = cw - wf;
            const unsigned int cc = cv[u];
            const float a00 = (float)(cc & 0xffu);
            const float a01 = (float)((cc >> 8) & 0xffu);
            const float a10 = (float)((cc >> 16) & 0xffu);
            const float a11 = (float)(cc >> 24);
            const float feat = a00 * (wh0 * ww0) + a01 * (wh0 * ww1)
                             + a10 * (wh1 * ww0) + a11 * (wh1 * ww1);
            acc += feat;
            mn = fminf(mn, feat);
        }
    }

    float mean = acc * (1.0f / (255.0f * 64.0f));
    const float mns = mn * (1.0f / 255.0f);

    // Conservative candidate test: exact detection implies u8 min/mean > RESCUE.
    bool det = false;
    if ((mns > RESCUE) && (mean > RESCUE) && (c != 0)) {
        // Exact recompute from fp32 heatmap, reference op order.
        float acc2 = 0.0f;
        float mn2  = __builtin_inff();
        for (int s = 0; s < 64; ++s) {
            const float t  = sample_t(s);
            const float om = 1.0f - t;
            float ch = __fadd_rn(__fmul_rn(jr.x, t), __fmul_rn(jjc.x, om));
            float cw = __fadd_rn(__fmul_rn(jr.y, t), __fmul_rn(jjc.y, om));
            ch = fminf(fmaxf(ch, 0.0f), 1023.0f);
            cw = fminf(fmaxf(cw, 0.0f), 1023.0f);
            const float hf = floorf(ch), hc = ceilf(ch);
            const float wf = floorf(cw), wc = ceilf(cw);
            const int hfi = (int)hf, hci = (int)hc;
            const int wfi = (int)wf, wci = (int)wc;
            const float a00 = heat[(hfi << 10) + wfi];
            const float a01 = heat[(hfi << 10) + wci];
            const float a10 = heat[(hci << 10) + wfi];
            const float a11 = heat[(hci << 10) + wci];
            const float t1 = __fmul_rn(__fmul_rn(a00, __fsub_rn(hc, ch)), __fsub_rn(wc, cw));
            const float t2 = __fmul_rn(__fmul_rn(a01, __fsub_rn(hc, ch)), __fsub_rn(cw, wf));
            const float t3 = __fmul_rn(__fmul_rn(a10, __fsub_rn(ch, hf)), __fsub_rn(wc, cw));
            const float t4 = __fmul_rn(__fmul_rn(a11, __fsub_rn(ch, hf)), __fsub_rn(cw, wf));
            const float feat = __fadd_rn(__fadd_rn(__fadd_rn(t1, t2), t3), t4);
            acc2 += feat;
            mn2 = fminf(mn2, feat);
        }
        mean = acc2 * (1.0f / 64.0f);
        det = (mean > DETECT) && (mn2 > DETECT);
    }

    const int p1 = (r << 10) + j;
    mean_out[p1] = mean;                 // coalesced (consecutive j per row)
    line_out[p1] = det ? 1.0f : 0.0f;
}

// Fill complement band (d = (j-i) mod 1024 in [513,1023]) from the mirror cell:
// out[i][j] = out[j][i]. LDS-tiled 64x64 transpose, both arrays, fully coalesced.
__global__ __launch_bounds__(256) void mirror_kernel(
    float* __restrict__ line_out, float* __restrict__ mean_out)
{
    __shared__ float lm[64][65];
    __shared__ float mm[64][65];
    const int bi = blockIdx.x >> 4;      // dst tile row block
    const int bj = blockIdx.x & 15;      // dst tile col block
    const int tx = threadIdx.x & 63;
    const int g  = threadIdx.x >> 6;     // 0..3

    // Load source tile: src row (64*bj + b), col (64*bi + tx)  -> lds[b][tx]
    #pragma unroll
    for (int k = 0; k < 16; ++k) {
        const int b = (g << 4) + k;
        const int src = ((bj << 6) + b) * 1024 + (bi << 6) + tx;
        lm[b][tx] = line_out[src];
        mm[b][tx] = mean_out[src];
    }
    __syncthreads();

    // Write dst row (64*bi + a), col (64*bj + tx) = lds[tx][a], predicated on band
    #pragma unroll
    for (int k = 0; k < 16; ++k) {
        const int a = (g << 4) + k;
        const int i = (bi << 6) + a;
        const int j = (bj << 6) + tx;
        const int d = (j - i) & 1023;
        if (d >= 513) {
            const int dst = i * 1024 + j;
            line_out[dst] = lm[tx][a];
            mean_out[dst] = mm[tx][a];
        }
    }
}

extern "C" void kernel_launch(void* const* d_in, const int* in_sizes, int n_in,
                              void* d_out, int out_size, void* d_ws, size_t ws_size,
                              hipStream_t stream) {
    const float* junc = (const float*)d_in[0];   // [1024,2] float32
    const float* heat = (const float*)d_in[1];   // [1024,1024] float32
    float* line_out = (float*)d_out;
    float* mean_out = line_out + NJ * NJ;

    unsigned int* packed = (unsigned int*)d_ws;  // 4 MB scratch
    pack_kernel<<<1024, 256, 0, stream>>>(heat, (uint4*)packed);

    const int total = NJ * 513;                  // 525,312 threads = 2052 blocks
    sold2_thread_kernel<<<total / 256, 256, 0, stream>>>(junc, heat, packed,
                                                         line_out, mean_out);

    mirror_kernel<<<256, 256, 0, stream>>>(line_out, mean_out);
}